// Round 1
// baseline (394.852 us; speedup 1.0000x reference)
//
#include <hip/hip_runtime.h>

#define BT   16
#define FIN  16
#define FOUT 32

// ---------------- CSR build ----------------

__global__ void hist_kernel(const int* __restrict__ rows, int* __restrict__ counts, int E) {
    int e = blockIdx.x * blockDim.x + threadIdx.x;
    if (e < E) atomicAdd(&counts[rows[e]], 1);
}

__global__ void scan_kernel(const int* __restrict__ counts, int* __restrict__ row_start, int N) {
    __shared__ int part[1024];
    int t = threadIdx.x;
    int per = (N + 1023) >> 10;
    int base = t * per;
    int s = 0;
    for (int i = 0; i < per; ++i) {
        int idx = base + i;
        if (idx < N) s += counts[idx];
    }
    part[t] = s;
    __syncthreads();
    // Hillis-Steele inclusive scan over 1024 partials
    for (int off = 1; off < 1024; off <<= 1) {
        int v = (t >= off) ? part[t - off] : 0;
        __syncthreads();
        part[t] += v;
        __syncthreads();
    }
    int run = (t == 0) ? 0 : part[t - 1];   // exclusive prefix of this thread's range
    for (int i = 0; i < per; ++i) {
        int idx = base + i;
        if (idx < N) {
            row_start[idx] = run;
            run += counts[idx];
        }
    }
    if (t == 1023) row_start[N] = part[1023];
}

__global__ void scatter_kernel(const int* __restrict__ rows, const int* __restrict__ cols,
                               const float* __restrict__ vals,
                               const int* __restrict__ row_start, int* __restrict__ cursor,
                               int* __restrict__ col_s, float* __restrict__ val_s, int E) {
    int e = blockIdx.x * blockDim.x + threadIdx.x;
    if (e >= E) return;
    int r = rows[e];
    int pos = row_start[r] + atomicAdd(&cursor[r], 1);
    col_s[pos] = cols[e];
    val_s[pos] = vals[e];
}

// ---------------- gate + transpose:  x[n][bt*16+f] = water[bt][n][f] * gate(bt,n) ----------------

__global__ __launch_bounds__(256) void gate_x_kernel(
        const float* __restrict__ water,  // [BT, N, 16]
        const float* __restrict__ st,     // [BT, N, 8]
        const float* __restrict__ Wg1, const float* __restrict__ bg1,
        const float* __restrict__ Wg2, const float* __restrict__ bg2,
        const float* __restrict__ min_gate,
        float* __restrict__ x, int N) {
    int t = blockIdx.x * blockDim.x + threadIdx.x;
    if (t >= N * BT) return;
    int bt = t & (BT - 1);
    int n  = t >> 4;

    const float4* sp = (const float4*)(st + ((size_t)bt * N + n) * 8);
    float4 s0 = sp[0], s1 = sp[1];
    float g1 = s0.x * Wg1[0] + s0.y * Wg1[1] + s0.z * Wg1[2] + bg1[0];
    float g2 = s0.w * Wg2[0] + s1.x * Wg2[1] + s1.y * Wg2[2] + s1.z * Wg2[3] + s1.w * Wg2[4] + bg2[0];
    g1 = 1.f / (1.f + __expf(-g1));
    g2 = 1.f / (1.f + __expf(-g2));
    float gate = fmaxf(g1 * g2, min_gate[0]);

    const float4* wp = (const float4*)(water + ((size_t)bt * N + n) * FIN);
    float4*       xp = (float4*)(x + ((size_t)n * BT + bt) * FIN);
#pragma unroll
    for (int k = 0; k < 4; ++k) {
        float4 w = wp[k];
        w.x *= gate; w.y *= gate; w.z *= gate; w.w *= gate;
        xp[k] = w;
    }
}

// ---------------- fused SpMM (gather) + 16->32 matmul + LayerNorm ----------------

__global__ __launch_bounds__(256) void spmm_ln_kernel(
        const float* __restrict__ x,          // [N, BT*FIN] = [N, 256]
        const int* __restrict__ row_start,    // [N+1]
        const int* __restrict__ col_s,
        const float* __restrict__ val_s,
        const float* __restrict__ W,          // [16, 32]
        const float* __restrict__ bvec,       // [32]
        const float* __restrict__ gamma,
        const float* __restrict__ beta,
        float* __restrict__ out, int N) {     // out: [BT, N, 32]
    __shared__ float hsh[BT][FIN + 1];
    __shared__ float Wsh[FIN][FOUT];

    int n = blockIdx.x;
    int t = threadIdx.x;
    int bt = t >> 4;
    int f  = t & 15;

    // stage W (512 floats) into LDS
    Wsh[t >> 5][t & 31]       = W[t];
    Wsh[(t >> 5) + 8][t & 31] = W[t + 256];

    int e0 = row_start[n], e1 = row_start[n + 1];
    float acc = 0.f;
    for (int e = e0; e < e1; ++e) {
        int   c = col_s[e];
        float v = val_s[e];
        acc += v * x[(size_t)c * (BT * FIN) + t];   // 256 lanes read 1KB contiguous
    }
    hsh[bt][f] = acc;
    __syncthreads();

    // out[bt][j] = b[j] + sum_f h[bt][f] * W[f][j];  thread handles j0=f, j1=f+16
    float o0 = bvec[f], o1 = bvec[f + 16];
#pragma unroll
    for (int k = 0; k < FIN; ++k) {
        float h = hsh[bt][k];
        o0 += h * Wsh[k][f];
        o1 += h * Wsh[k][f + 16];
    }

    // LayerNorm over the 32 outputs of this (bt, n): 16 lanes x 2 values
    float s  = o0 + o1;
    float sq = o0 * o0 + o1 * o1;
#pragma unroll
    for (int off = 8; off >= 1; off >>= 1) {
        s  += __shfl_xor(s,  off, 16);
        sq += __shfl_xor(sq, off, 16);
    }
    float mu  = s * (1.f / 32.f);
    float var = sq * (1.f / 32.f) - mu * mu;
    float inv = rsqrtf(var + 1e-3f);
    o0 = (o0 - mu) * inv * gamma[f]      + beta[f];
    o1 = (o1 - mu) * inv * gamma[f + 16] + beta[f + 16];

    float* op = out + (size_t)bt * N * FOUT + (size_t)n * FOUT;
    op[f]      = o0;
    op[f + 16] = o1;
}

// ---------------- launch ----------------

extern "C" void kernel_launch(void* const* d_in, const int* in_sizes, int n_in,
                              void* d_out, int out_size, void* d_ws, size_t ws_size,
                              hipStream_t stream) {
    const float* water    = (const float*)d_in[0];
    const float* st       = (const float*)d_in[1];
    const int*   adj_rows = (const int*)  d_in[2];
    const int*   adj_cols = (const int*)  d_in[3];
    const float* adj_vals = (const float*)d_in[4];
    const float* W_feat   = (const float*)d_in[5];
    const float* b_feat   = (const float*)d_in[6];
    const float* Wg1      = (const float*)d_in[7];
    const float* bg1      = (const float*)d_in[8];
    const float* Wg2      = (const float*)d_in[9];
    const float* bg2      = (const float*)d_in[10];
    const float* ln_gamma = (const float*)d_in[11];
    const float* ln_beta  = (const float*)d_in[12];
    const float* min_gate = (const float*)d_in[13];
    float* out = (float*)d_out;

    int N = in_sizes[0] / (BT * FIN);
    int E = in_sizes[2];

    char* ws = (char*)d_ws;
    size_t off = 0;
    auto alloc = [&](size_t bytes) -> void* {
        off = (off + 255) & ~(size_t)255;
        void* p = ws + off;
        off += bytes;
        return p;
    };
    int*   counts    = (int*)  alloc((size_t)N * sizeof(int));
    int*   cursor    = (int*)  alloc((size_t)N * sizeof(int));
    int*   row_start = (int*)  alloc((size_t)(N + 1) * sizeof(int));
    int*   col_s     = (int*)  alloc((size_t)E * sizeof(int));
    float* val_s     = (float*)alloc((size_t)E * sizeof(float));
    float* x         = (float*)alloc((size_t)N * BT * FIN * sizeof(float));

    hipMemsetAsync(counts, 0, (size_t)N * sizeof(int), stream);
    hipMemsetAsync(cursor, 0, (size_t)N * sizeof(int), stream);

    int eb = (E + 255) / 256;
    hist_kernel<<<eb, 256, 0, stream>>>(adj_rows, counts, E);
    scan_kernel<<<1, 1024, 0, stream>>>(counts, row_start, N);
    scatter_kernel<<<eb, 256, 0, stream>>>(adj_rows, adj_cols, adj_vals,
                                           row_start, cursor, col_s, val_s, E);
    gate_x_kernel<<<(N * BT + 255) / 256, 256, 0, stream>>>(
        water, st, Wg1, bg1, Wg2, bg2, min_gate, x, N);
    spmm_ln_kernel<<<N, 256, 0, stream>>>(
        x, row_start, col_s, val_s, W_feat, b_feat, ln_gamma, ln_beta, out, N);
}